// Round 1
// baseline (220.283 us; speedup 1.0000x reference)
//
#include <hip/hip_runtime.h>

constexpr int TPB = 256;
constexpr int DIM = 300;   // embedding dim
constexpr int H1N = 64;
constexpr int H2N = 32;
constexpr int NA  = 18;    // attribute dims
constexpr int NK  = 32;    // negatives
constexpr int NC  = 384;   // codebook size
constexpr int KP  = 25;    // k-panel for x staging (300 = 12 * 25)
constexpr int NPANEL = DIM / KP;
constexpr float LOG_HALF = -0.6931471805599453f;

__device__ __forceinline__ float fast_sigmoid(float z) {
    return __builtin_amdgcn_rcpf(1.0f + __expf(-z));
}
// numerically stable log(sigmoid(z)) = min(z,0) - log1p(exp(-|z|))
__device__ __forceinline__ float lsig(float z) {
    return fminf(z, 0.0f) - __logf(1.0f + __expf(-fabsf(z)));
}

__global__ void init_ws_k(double* s, unsigned* c) { *s = 0.0; *c = 0u; }

__global__ __launch_bounds__(TPB, 2)
void fused_mf2(const float* __restrict__ x, const float* __restrict__ y,
               const float* __restrict__ ob, const float* __restrict__ cbf,
               const float* __restrict__ W1, const float* __restrict__ b1,
               const float* __restrict__ W2, const float* __restrict__ b2,
               const float* __restrict__ W3, const float* __restrict__ b3,
               const int* __restrict__ neg_idx,
               float* __restrict__ out_wu,
               double* __restrict__ loss_sum, unsigned* __restrict__ mask_cnt)
{
    __shared__ float lds_x[2][TPB * KP];   // 2 x 25.6 KB double buffer
    __shared__ unsigned cb_bits[NC];       // packed binary codebook rows
    __shared__ float wred[TPB / 64];
    __shared__ int   mred[TPB / 64];

    const int  tid  = threadIdx.x;
    const long brow = (long)blockIdx.x * TPB;
    const long b    = brow + tid;          // this thread's row

    // pack codebook into 18-bit masks (rows are exactly 0.0/1.0)
    for (int c = tid; c < NC; c += TPB) {
        unsigned bits = 0u;
        #pragma unroll
        for (int a = 0; a < NA; ++a)
            bits |= (cbf[c * NA + a] != 0.0f) ? (1u << a) : 0u;
        cb_bits[c] = bits;
    }

    const float* xbase = x + brow * DIM;

    // ---- prologue: stage panel 0 ----
    float stg[KP];
    #pragma unroll
    for (int q = 0; q < KP; ++q) {
        int idx = q * TPB + tid;
        int r = idx / KP;
        int c = idx - r * KP;
        stg[q] = xbase[r * DIM + c];
    }
    #pragma unroll
    for (int q = 0; q < KP; ++q)
        lds_x[0][q * TPB + tid] = stg[q];
    __syncthreads();

    float acc1[H1N];
    #pragma unroll
    for (int j = 0; j < H1N; ++j) acc1[j] = 0.0f;

    // ---- x @ W1, double-buffered panels ----
    int buf = 0;
    for (int p = 0; p < NPANEL; ++p) {
        if (p + 1 < NPANEL) {               // prefetch next panel into regs
            #pragma unroll
            for (int q = 0; q < KP; ++q) {
                int idx = q * TPB + tid;
                int r = idx / KP;
                int c = idx - r * KP;
                stg[q] = xbase[r * DIM + (p + 1) * KP + c];
            }
        }
        const float* lx  = &lds_x[buf][tid * KP];
        const float* w1p = W1 + p * KP * H1N;
        #pragma unroll 5
        for (int i = 0; i < KP; ++i) {
            float xv = lx[i];
            const float* wrow = w1p + i * H1N;  // wave-uniform -> s_load
            #pragma unroll
            for (int j = 0; j < H1N; ++j)
                acc1[j] = fmaf(xv, wrow[j], acc1[j]);
        }
        __syncthreads();
        if (p + 1 < NPANEL) {
            #pragma unroll
            for (int q = 0; q < KP; ++q)
                lds_x[buf ^ 1][q * TPB + tid] = stg[q];
            __syncthreads();
        }
        buf ^= 1;
    }

    #pragma unroll
    for (int j = 0; j < H1N; ++j)
        acc1[j] = fast_sigmoid(acc1[j] + b1[j]);

    // ---- h1 @ W2 (all in registers, W2 wave-uniform) ----
    float acc2[H2N];
    #pragma unroll
    for (int j = 0; j < H2N; ++j) acc2[j] = b2[j];
    #pragma unroll 8
    for (int i = 0; i < H1N; ++i) {
        const float hv = acc1[i];
        const float* wrow = W2 + i * H2N;
        #pragma unroll
        for (int j = 0; j < H2N; ++j)
            acc2[j] = fmaf(hv, wrow[j], acc2[j]);
    }
    #pragma unroll
    for (int j = 0; j < H2N; ++j) acc2[j] = fast_sigmoid(acc2[j]);

    // ---- h2 @ W3 -> W_user[18] ----
    float wu[NA];
    #pragma unroll
    for (int a = 0; a < NA; ++a) wu[a] = b3[a];
    #pragma unroll
    for (int i = 0; i < H2N; ++i) {
        const float hv = acc2[i];
        const float* wrow = W3 + i * NA;
        #pragma unroll
        for (int a = 0; a < NA; ++a)
            wu[a] = fmaf(hv, wrow[a], wu[a]);
    }

    // store W_user (output 0)
    float2* op = reinterpret_cast<float2*>(out_wu + b * NA);
    #pragma unroll
    for (int q = 0; q < NA / 2; ++q)
        op[q] = make_float2(wu[2 * q], wu[2 * q + 1]);

    // ---- W_compact = W_user * ob, mask = (row sum != 0) ----
    const float2* obp = reinterpret_cast<const float2*>(ob + b * NA);
    float wc[NA];
    #pragma unroll
    for (int q = 0; q < NA / 2; ++q) {
        float2 o = obp[q];
        wc[2 * q]     = wu[2 * q]     * o.x;
        wc[2 * q + 1] = wu[2 * q + 1] * o.y;
    }
    float ssum = 0.0f;
    #pragma unroll
    for (int a = 0; a < NA; ++a) ssum += wc[a];
    const int mask = (ssum != 0.0f) ? 1 : 0;

    // ---- negatives: per-attribute counts via packed codebook bits ----
    int cnt[NA];
    #pragma unroll
    for (int a = 0; a < NA; ++a) cnt[a] = 0;
    const int4* nb = reinterpret_cast<const int4*>(neg_idx + b * NK);
    #pragma unroll
    for (int kq = 0; kq < NK / 4; ++kq) {
        const int4 iv = nb[kq];
        const int ids[4] = {iv.x, iv.y, iv.z, iv.w};
        #pragma unroll
        for (int u = 0; u < 4; ++u) {
            const unsigned bits = cb_bits[ids[u]];
            #pragma unroll
            for (int a = 0; a < NA; ++a)
                cnt[a] += (int)((bits >> a) & 1u);
        }
    }

    // ---- pos_log + neg_log (y is binary) ----
    const float2* yp = reinterpret_cast<const float2*>(y + b * NA);
    float rsum = 0.0f;
    #pragma unroll
    for (int q = 0; q < NA / 2; ++q) {
        const float2 yv = yp[q];
        #pragma unroll
        for (int h = 0; h < 2; ++h) {
            const int a = 2 * q + h;
            const float yva = h ? yv.y : yv.x;
            const float w = wc[a];
            const float pos = (yva != 0.0f) ? lsig(w) : LOG_HALF;
            const float nl  = lsig(-w);
            rsum += pos + (float)cnt[a] * nl + (float)(NK - cnt[a]) * LOG_HALF;
        }
    }

    // ---- block reduce masked (pos+neg) and mask count ----
    float v = mask ? rsum : 0.0f;
    #pragma unroll
    for (int off = 32; off > 0; off >>= 1) v += __shfl_down(v, off);
    int m = mask;
    #pragma unroll
    for (int off = 32; off > 0; off >>= 1) m += __shfl_down(m, off);
    if ((tid & 63) == 0) { wred[tid >> 6] = v; mred[tid >> 6] = m; }
    __syncthreads();
    if (tid == 0) {
        float bs = 0.0f; int bm = 0;
        #pragma unroll
        for (int w = 0; w < TPB / 64; ++w) { bs += wred[w]; bm += mred[w]; }
        atomicAdd(loss_sum, (double)bs);
        atomicAdd(mask_cnt, (unsigned)bm);
    }
}

__global__ void finalize_k(const double* loss_sum, const unsigned* mask_cnt,
                           float* out_loss) {
    const float c = fmaxf((float)(*mask_cnt), 1.0f);
    out_loss[0] = (float)(-(*loss_sum) / (double)c);
}

extern "C" void kernel_launch(void* const* d_in, const int* in_sizes, int n_in,
                              void* d_out, int out_size, void* d_ws, size_t ws_size,
                              hipStream_t stream)
{
    const float* x   = (const float*)d_in[0];
    const float* y   = (const float*)d_in[1];
    const float* ob  = (const float*)d_in[2];
    const float* cb  = (const float*)d_in[3];
    const float* W1  = (const float*)d_in[4];
    const float* b1  = (const float*)d_in[5];
    const float* W2  = (const float*)d_in[6];
    const float* b2  = (const float*)d_in[7];
    const float* W3  = (const float*)d_in[8];
    const float* b3  = (const float*)d_in[9];
    const int*   neg = (const int*)d_in[10];

    const int B = in_sizes[0] / DIM;       // 131072, divisible by TPB

    float* out_wu = (float*)d_out;
    double*   ls  = (double*)d_ws;
    unsigned* mc  = (unsigned*)(ls + 1);

    init_ws_k<<<1, 1, 0, stream>>>(ls, mc);
    fused_mf2<<<B / TPB, TPB, 0, stream>>>(x, y, ob, cb, W1, b1, W2, b2, W3, b3,
                                           neg, out_wu, ls, mc);
    finalize_k<<<1, 1, 0, stream>>>(ls, mc, out_wu + (long)B * NA);
}

// Round 2
// 148.133 us; speedup vs baseline: 1.4871x; 1.4871x over previous
//
#include <hip/hip_runtime.h>

constexpr int TPB = 256;
constexpr int RPB = 64;    // rows per block
constexpr int DIM = 300;   // embedding dim
constexpr int H1N = 64;
constexpr int H2N = 32;
constexpr int NA  = 18;    // attribute dims
constexpr int NK  = 32;    // negatives
constexpr int NC  = 384;   // codebook size
constexpr int KP  = 20;    // k-panel width (300 = 15 * 20)
constexpr int NPANEL = DIM / KP;
constexpr int JT  = 16;    // h1 outputs per thread (64/4 quarters)
constexpr int EPT = RPB * KP / TPB;  // 5 staging elements per thread
constexpr float LOG_HALF = -0.6931471805599453f;

__device__ __forceinline__ float fast_sigmoid(float z) {
    return __builtin_amdgcn_rcpf(1.0f + __expf(-z));
}
// numerically stable log(sigmoid(z)) = min(z,0) - log1p(exp(-|z|))
__device__ __forceinline__ float lsig(float z) {
    return fminf(z, 0.0f) - __logf(1.0f + __expf(-fabsf(z)));
}

__global__ void init_ws_k(double* s, unsigned* c) { *s = 0.0; *c = 0u; }

union SmemU {
    float xpan[2][KP][RPB + 1];   // column-major x panels, +1 pad: banks spread
    float h1buf[RPB][H1N + 1];    // h1 exchange, +1 pad: conflict-free row reads
};

__global__ __launch_bounds__(TPB, 8)
void fused_mf2(const float* __restrict__ x, const float* __restrict__ y,
               const float* __restrict__ ob, const float* __restrict__ cbf,
               const float* __restrict__ W1, const float* __restrict__ b1,
               const float* __restrict__ W2, const float* __restrict__ b2,
               const float* __restrict__ W3, const float* __restrict__ b3,
               const int* __restrict__ neg_idx,
               float* __restrict__ out_wu,
               double* __restrict__ loss_sum, unsigned* __restrict__ mask_cnt)
{
    __shared__ SmemU u;
    __shared__ unsigned cb_bits[NC];

    const int tid = threadIdx.x;
    const int row = tid & (RPB - 1);
    const int qq  = __builtin_amdgcn_readfirstlane(tid >> 6);  // wave id = quarter
    const long brow = (long)blockIdx.x * RPB;

    // pack binary codebook rows into 18-bit masks
    for (int c = tid; c < NC; c += TPB) {
        unsigned bits = 0u;
        #pragma unroll
        for (int a = 0; a < NA; ++a)
            bits |= (cbf[c * NA + a] != 0.0f) ? (1u << a) : 0u;
        cb_bits[c] = bits;
    }

    const float* xbase = x + brow * DIM;

    // ---- prologue: stage panel 0 (column-major into LDS) ----
    #pragma unroll
    for (int q = 0; q < EPT; ++q) {
        const int idx = q * TPB + tid;
        const int r = idx / KP, c = idx - r * KP;
        u.xpan[0][c][r] = xbase[r * DIM + c];
    }
    __syncthreads();   // also covers cb_bits

    float acc1[JT];
    #pragma unroll
    for (int j = 0; j < JT; ++j) acc1[j] = b1[qq * JT + j];

    float stg[EPT];
    // ---- x @ W1 quarter, double-buffered panels ----
    for (int p = 0; p < NPANEL; ++p) {
        const int bb = p & 1;
        if (p + 1 < NPANEL) {          // prefetch next panel into regs
            #pragma unroll
            for (int q = 0; q < EPT; ++q) {
                const int idx = q * TPB + tid;
                const int r = idx / KP, c = idx - r * KP;
                stg[q] = xbase[r * DIM + (p + 1) * KP + c];
            }
        }
        const float* w1p = W1 + p * KP * H1N + qq * JT;   // wave-uniform -> s_load
        #pragma unroll
        for (int i = 0; i < KP; ++i) {
            const float xv = u.xpan[bb][i][row];          // broadcast-friendly b32
            #pragma unroll
            for (int j = 0; j < JT; ++j)
                acc1[j] = fmaf(xv, w1p[i * H1N + j], acc1[j]);
        }
        __syncthreads();
        if (p + 1 < NPANEL) {
            #pragma unroll
            for (int q = 0; q < EPT; ++q) {
                const int idx = q * TPB + tid;
                const int r = idx / KP, c = idx - r * KP;
                u.xpan[bb ^ 1][c][r] = stg[q];
            }
            __syncthreads();
        }
    }

    // ---- exchange h1 quarters through LDS (xpan is dead past the last sync) ----
    #pragma unroll
    for (int j = 0; j < JT; ++j)
        u.h1buf[row][qq * JT + j] = fast_sigmoid(acc1[j]);
    __syncthreads();

    if (tid >= RPB) return;            // waves 1-3 done; wave 0 runs downstream

    const long b = brow + tid;

    // ---- h1 @ W2 ----
    float acc2[H2N];
    #pragma unroll
    for (int j = 0; j < H2N; ++j) acc2[j] = b2[j];
    #pragma unroll 4
    for (int i = 0; i < H1N; ++i) {
        const float hv = u.h1buf[tid][i];
        const float* wr = W2 + i * H2N;
        #pragma unroll
        for (int j = 0; j < H2N; ++j)
            acc2[j] = fmaf(hv, wr[j], acc2[j]);
    }
    #pragma unroll
    for (int j = 0; j < H2N; ++j) acc2[j] = fast_sigmoid(acc2[j]);

    // ---- h2 @ W3 -> W_user[18] ----
    float wu[NA];
    #pragma unroll
    for (int a = 0; a < NA; ++a) wu[a] = b3[a];
    #pragma unroll
    for (int i = 0; i < H2N; ++i) {
        const float hv = acc2[i];
        const float* wr = W3 + i * NA;
        #pragma unroll
        for (int a = 0; a < NA; ++a)
            wu[a] = fmaf(hv, wr[a], wu[a]);
    }

    // store W_user (output 0)
    float* op = out_wu + b * NA;
    #pragma unroll
    for (int a = 0; a < NA; ++a) op[a] = wu[a];

    // ---- W_compact, mask ----
    const float* obp = ob + b * NA;
    float wc[NA];
    float ssum = 0.0f;
    #pragma unroll
    for (int a = 0; a < NA; ++a) { wc[a] = wu[a] * obp[a]; ssum += wc[a]; }
    const int mask = (ssum != 0.0f) ? 1 : 0;

    // ---- negatives: per-attribute counts via packed codebook bits ----
    const int4* nb = reinterpret_cast<const int4*>(neg_idx + b * NK);
    int cnt[NA];
    #pragma unroll
    for (int a = 0; a < NA; ++a) cnt[a] = 0;
    #pragma unroll
    for (int kq = 0; kq < NK / 4; ++kq) {
        const int4 iv = nb[kq];
        const int ids[4] = {iv.x, iv.y, iv.z, iv.w};
        #pragma unroll
        for (int uu = 0; uu < 4; ++uu) {
            const unsigned bits = cb_bits[ids[uu]];
            #pragma unroll
            for (int a = 0; a < NA; ++a)
                cnt[a] += (int)((bits >> a) & 1u);
        }
    }

    // ---- pos_log + neg_log (y, codebook binary) ----
    const float* yp = y + b * NA;
    float rsum = 0.0f;
    #pragma unroll
    for (int a = 0; a < NA; ++a) {
        const float w = wc[a];
        const float pos = (yp[a] != 0.0f) ? lsig(w) : LOG_HALF;
        rsum += pos + (float)cnt[a] * lsig(-w) + (float)(NK - cnt[a]) * LOG_HALF;
    }

    // ---- wave-0 reduction, one atomic per block ----
    float v = mask ? rsum : 0.0f;
    int   m = mask;
    #pragma unroll
    for (int off = 32; off > 0; off >>= 1) {
        v += __shfl_down(v, off);
        m += __shfl_down(m, off);
    }
    if (tid == 0) {
        atomicAdd(loss_sum, (double)v);
        atomicAdd(mask_cnt, (unsigned)m);
    }
}

__global__ void finalize_k(const double* loss_sum, const unsigned* mask_cnt,
                           float* out_loss) {
    const float c = fmaxf((float)(*mask_cnt), 1.0f);
    out_loss[0] = (float)(-(*loss_sum) / (double)c);
}

extern "C" void kernel_launch(void* const* d_in, const int* in_sizes, int n_in,
                              void* d_out, int out_size, void* d_ws, size_t ws_size,
                              hipStream_t stream)
{
    const float* x   = (const float*)d_in[0];
    const float* y   = (const float*)d_in[1];
    const float* ob  = (const float*)d_in[2];
    const float* cb  = (const float*)d_in[3];
    const float* W1  = (const float*)d_in[4];
    const float* b1  = (const float*)d_in[5];
    const float* W2  = (const float*)d_in[6];
    const float* b2  = (const float*)d_in[7];
    const float* W3  = (const float*)d_in[8];
    const float* b3  = (const float*)d_in[9];
    const int*   neg = (const int*)d_in[10];

    const int B = in_sizes[0] / DIM;   // 131072, divisible by RPB

    float* out_wu = (float*)d_out;
    double*   ls  = (double*)d_ws;
    unsigned* mc  = (unsigned*)(ls + 1);

    init_ws_k<<<1, 1, 0, stream>>>(ls, mc);
    fused_mf2<<<B / RPB, TPB, 0, stream>>>(x, y, ob, cb, W1, b1, W2, b2, W3, b3,
                                           neg, out_wu, ls, mc);
    finalize_k<<<1, 1, 0, stream>>>(ls, mc, out_wu + (long)B * NA);
}

// Round 3
// 94.256 us; speedup vs baseline: 2.3371x; 1.5716x over previous
//
#include <hip/hip_runtime.h>

typedef short bf16x8 __attribute__((ext_vector_type(8)));
typedef unsigned short u16;
typedef u16 u16x8 __attribute__((ext_vector_type(8)));
typedef float f32x4 __attribute__((ext_vector_type(4)));

constexpr int TPB  = 256;
constexpr int RPB  = 64;    // rows per block
constexpr int DIM  = 300;   // embedding dim
constexpr int KPAD = 320;   // K padded to 10*32
constexpr int NKT  = 10;    // K-steps of 32
constexpr int H1N  = 64;
constexpr int NA   = 18;
constexpr int NK   = 32;
constexpr int NC   = 384;
constexpr float LOG_HALF = -0.6931471805599453f;

__device__ __forceinline__ float fast_sigmoid(float z) {
    return __builtin_amdgcn_rcpf(1.0f + __expf(-z));
}
// stable log(sigmoid(z))
__device__ __forceinline__ float lsig(float z) {
    return fminf(z, 0.0f) - __logf(1.0f + __expf(-fabsf(z)));
}
// f32 -> bf16 (RNE) bit pattern
__device__ __forceinline__ u16 f2bf(float f) {
    unsigned u = __builtin_bit_cast(unsigned, f);
    unsigned r = (u + 0x7FFFu + ((u >> 16) & 1u)) >> 16;
    return (u16)r;
}
__device__ __forceinline__ float bf2f(u16 h) {
    return __builtin_bit_cast(float, ((unsigned)h) << 16);
}
// spread 8 bits to 8 nibbles (bit a -> bit 4a)
__device__ __forceinline__ unsigned spread8(unsigned v) {
    v = (v | (v << 12)) & 0x000F000Fu;
    v = (v | (v << 6))  & 0x03030303u;
    v = (v | (v << 3))  & 0x11111111u;
    return v;
}

__global__ __launch_bounds__(TPB, 3)
void fused_mf2(const float* __restrict__ x, const float* __restrict__ y,
               const float* __restrict__ ob, const float* __restrict__ cbf,
               const float* __restrict__ W1, const float* __restrict__ b1,
               const float* __restrict__ W2, const float* __restrict__ b2,
               const float* __restrict__ W3, const float* __restrict__ b3,
               const int* __restrict__ neg_idx,
               float* __restrict__ out_wu, float2* __restrict__ blk_part)
{
    __shared__ u16 xs[RPB * KPAD];     // 40 KiB, XOR-swizzled bf16 x tile
    __shared__ u16 h1s[RPB * H1N];     // 8 KiB, XOR-swizzled bf16 h1
    __shared__ unsigned cb_bits[NC];   // packed binary codebook rows
    __shared__ float wsum[4];
    __shared__ int   wcnt[4];

    const int tid  = threadIdx.x;
    const int lane = tid & 63;
    const int wv   = tid >> 6;
    const long brow = (long)blockIdx.x * RPB;
    const float* xg = x + brow * DIM;

    // ---- codebook bitmasks (rows are exactly 0/1) ----
    for (int c = tid; c < NC; c += TPB) {
        unsigned bits = 0u;
        #pragma unroll
        for (int a = 0; a < NA; ++a)
            bits |= (cbf[c * NA + a] != 0.0f) ? (1u << a) : 0u;
        cb_bits[c] = bits;
    }

    // ---- stage x tile f32 -> bf16 into swizzled LDS (coalesced dword loads) ----
    #pragma unroll
    for (int ch = 0; ch < 5; ++ch) {
        float v[15];
        #pragma unroll
        for (int j = 0; j < 15; ++j)
            v[j] = xg[(ch * 15 + j) * TPB + tid];
        #pragma unroll
        for (int j = 0; j < 15; ++j) {
            int idx = (ch * 15 + j) * TPB + tid;   // 0..19199
            int row = idx / DIM;                    // magic-mul
            int k   = idx - row * DIM;
            xs[(row * KPAD + k) ^ ((row & 7) << 3)] = f2bf(v[j]);
        }
    }
    // zero-pad k in [300,320)
    #pragma unroll
    for (int u = 0; u < 5; ++u) {
        int e = u * TPB + tid;                      // 0..1279 (= 64*20)
        int row = e / 20;
        int kp  = e - row * 20;
        xs[(row * KPAD + DIM + kp) ^ ((row & 7) << 3)] = 0;
    }

    // ---- W1 B-fragments resident in VGPRs (wave wv owns cols 16wv..16wv+15) ----
    const int colB = wv * 16 + (lane & 15);
    const int kg   = (lane >> 4) * 8;               // k-group within K=32 step
    bf16x8 bfr[NKT];
    #pragma unroll
    for (int kt = 0; kt < NKT; ++kt) {
        #pragma unroll
        for (int r = 0; r < 8; ++r) {
            int kk = kt * 32 + kg + r;
            float w = (kk < DIM) ? W1[kk * H1N + colB] : 0.0f;
            bfr[kt][r] = (short)f2bf(w);
        }
    }

    __syncthreads();

    // ---- MFMA: 4 row-tiles x 10 K-steps, acc in f32 ----
    f32x4 acc[4];
    #pragma unroll
    for (int rt = 0; rt < 4; ++rt) acc[rt] = (f32x4){0.f, 0.f, 0.f, 0.f};
    #pragma unroll
    for (int kt = 0; kt < NKT; ++kt) {
        #pragma unroll
        for (int rt = 0; rt < 4; ++rt) {
            int row = rt * 16 + (lane & 15);
            int idx = (row * KPAD + kt * 32 + kg) ^ ((row & 7) << 3);
            bf16x8 a = *(const bf16x8*)(xs + idx);
            acc[rt] = __builtin_amdgcn_mfma_f32_16x16x32_bf16(a, bfr[kt], acc[rt], 0, 0, 0);
        }
    }

    // ---- epilogue: bias + sigmoid -> h1s (bf16, swizzled) ----
    const float b1v = b1[wv * 16 + (lane & 15)];
    #pragma unroll
    for (int rt = 0; rt < 4; ++rt) {
        #pragma unroll
        for (int j = 0; j < 4; ++j) {
            int row = rt * 16 + (lane >> 4) * 4 + j;     // m89 C/D mapping
            float h = fast_sigmoid(acc[rt][j] + b1v);
            h1s[(row * H1N + wv * 16 + (lane & 15)) ^ ((row & 7) << 3)] = f2bf(h);
        }
    }
    __syncthreads();

    // ================= downstream: 4 lanes per row =================
    const int rloc = wv * 16 + (lane >> 2);   // row within block
    const int p    = lane & 3;                // part (j-split)
    const long b   = brow + rloc;

    // h1 row into registers (broadcast x4 across parts -> conflict-free)
    u16x8 h1r[8];
    #pragma unroll
    for (int q = 0; q < 8; ++q)
        h1r[q] = *(const u16x8*)(h1s + ((rloc * H1N + q * 8) ^ ((rloc & 7) << 3)));

    // ---- h1 @ W2 : part p owns cols p*8..p*8+7 over all 64 i ----
    float acc2[8];
    #pragma unroll
    for (int j = 0; j < 8; ++j) acc2[j] = b2[p * 8 + j];
    #pragma unroll
    for (int i = 0; i < H1N; ++i) {
        float hv = bf2f((u16)h1r[i >> 3][i & 7]);
        const float4 wa = *(const float4*)(W2 + i * 32 + p * 8);
        const float4 wb = *(const float4*)(W2 + i * 32 + p * 8 + 4);
        acc2[0] = fmaf(hv, wa.x, acc2[0]);
        acc2[1] = fmaf(hv, wa.y, acc2[1]);
        acc2[2] = fmaf(hv, wa.z, acc2[2]);
        acc2[3] = fmaf(hv, wa.w, acc2[3]);
        acc2[4] = fmaf(hv, wb.x, acc2[4]);
        acc2[5] = fmaf(hv, wb.y, acc2[5]);
        acc2[6] = fmaf(hv, wb.z, acc2[6]);
        acc2[7] = fmaf(hv, wb.w, acc2[7]);
    }
    float h2[8];
    #pragma unroll
    for (int j = 0; j < 8; ++j) h2[j] = fast_sigmoid(acc2[j]);

    // ---- h2 @ W3 : i-split (part p holds h2 cols p*8..+8), reduce over parts ----
    float wu[NA];
    #pragma unroll
    for (int a = 0; a < NA; ++a) wu[a] = 0.0f;
    #pragma unroll
    for (int uI = 0; uI < 8; ++uI) {
        const float hv = h2[uI];
        const float* w3r = W3 + (p * 8 + uI) * NA;
        #pragma unroll
        for (int a = 0; a < NA; ++a) wu[a] = fmaf(hv, w3r[a], wu[a]);
    }
    #pragma unroll
    for (int a = 0; a < NA; ++a) {
        wu[a] += __shfl_xor(wu[a], 1);
        wu[a] += __shfl_xor(wu[a], 2);
        wu[a] += b3[a];
    }

    // ---- negatives: per-part (8 negs) nibble-packed per-attr counts ----
    const int4* nb = reinterpret_cast<const int4*>(neg_idx + b * NK + p * 8);
    const int4 n0 = nb[0], n1 = nb[1];
    const int ids[8] = {n0.x, n0.y, n0.z, n0.w, n1.x, n1.y, n1.z, n1.w};
    unsigned c0 = 0u, c1 = 0u, c2 = 0u;
    #pragma unroll
    for (int kk = 0; kk < 8; ++kk) {
        unsigned bits = cb_bits[ids[kk]];
        c0 += spread8(bits & 0xFFu);
        c1 += spread8((bits >> 8) & 0xFFu);
        unsigned t = (bits >> 16) & 3u;
        c2 += (t | (t << 3)) & 0x11u;
    }
    // widen nibbles to bytes, reduce across the 4 parts (all lanes active)
    unsigned e0 = c0 & 0x0F0F0F0Fu;          // attrs 0,2,4,6
    unsigned e1 = (c0 >> 4) & 0x0F0F0F0Fu;   // attrs 1,3,5,7
    unsigned e2 = c1 & 0x0F0F0F0Fu;          // attrs 8,10,12,14
    unsigned e3 = (c1 >> 4) & 0x0F0F0F0Fu;   // attrs 9,11,13,15
    unsigned e4 = (c2 & 15u) | (((c2 >> 4) & 15u) << 8);  // attrs 16,17
    e0 += __shfl_xor((int)e0, 1); e0 += __shfl_xor((int)e0, 2);
    e1 += __shfl_xor((int)e1, 1); e1 += __shfl_xor((int)e1, 2);
    e2 += __shfl_xor((int)e2, 1); e2 += __shfl_xor((int)e2, 2);
    e3 += __shfl_xor((int)e3, 1); e3 += __shfl_xor((int)e3, 2);
    e4 += __shfl_xor((int)e4, 1); e4 += __shfl_xor((int)e4, 2);

    // ---- owned attrs: p<2 -> {4p..4p+3, 16+p}; p>=2 -> {4p..4p+3} ----
    float ssum = 0.0f;
    float wcv[5], yvv[5];
    #pragma unroll
    for (int t = 0; t < 5; ++t) {
        const bool act = (t < 4) || (p < 2);
        if (act) {
            const int a = (t < 4) ? (p * 4 + t) : (16 + p);
            float wuv;
            if (t < 4) wuv = (p == 0) ? wu[t] : (p == 1) ? wu[4 + t]
                             : (p == 2) ? wu[8 + t] : wu[12 + t];
            else       wuv = (p == 0) ? wu[16] : wu[17];
            out_wu[b * NA + a] = wuv;
            const float obv = ob[b * NA + a];
            yvv[t] = y[b * NA + a];
            const float wc = wuv * obv;
            wcv[t] = wc;
            ssum += wc;
        } else { wcv[t] = 0.0f; yvv[t] = 0.0f; }
    }
    ssum += __shfl_xor(ssum, 1);
    ssum += __shfl_xor(ssum, 2);
    const int mask = (ssum != 0.0f) ? 1 : 0;

    float rsum = 0.0f;
    #pragma unroll
    for (int t = 0; t < 5; ++t) {
        const bool act = (t < 4) || (p < 2);
        if (act) {
            unsigned reg;
            int sh;
            if (t < 4) {
                reg = ((t & 1) == 0) ? ((p < 2) ? e0 : e2) : ((p < 2) ? e1 : e3);
                sh  = (((p & 1) * 2) + (t >> 1)) * 8;
            } else {
                reg = e4;
                sh  = p * 8;
            }
            const int cn = (int)((reg >> sh) & 0xFFu);
            const float w = wcv[t];
            const float pos = (yvv[t] != 0.0f) ? lsig(w) : LOG_HALF;
            rsum += pos + (float)cn * lsig(-w) + (float)(NK - cn) * LOG_HALF;
        }
    }
    rsum += __shfl_xor(rsum, 1);
    rsum += __shfl_xor(rsum, 2);

    // ---- block reduction (no atomics): per-block partial to workspace ----
    float v = (p == 0 && mask) ? rsum : 0.0f;
    int   m = (p == 0) ? mask : 0;
    #pragma unroll
    for (int off = 32; off > 0; off >>= 1) {
        v += __shfl_down(v, off);
        m += __shfl_down(m, off);
    }
    if (lane == 0) { wsum[wv] = v; wcnt[wv] = m; }
    __syncthreads();
    if (tid == 0) {
        float s = wsum[0] + wsum[1] + wsum[2] + wsum[3];
        int   c = wcnt[0] + wcnt[1] + wcnt[2] + wcnt[3];
        blk_part[blockIdx.x] = make_float2(s, (float)c);
    }
}

__global__ void finalize_k(const float2* __restrict__ part, int nblk,
                           float* __restrict__ out_loss) {
    __shared__ float ss[4], sc[4];
    float s = 0.f, c = 0.f;
    for (int i = threadIdx.x; i < nblk; i += 256) {
        float2 v = part[i];
        s += v.x; c += v.y;
    }
    #pragma unroll
    for (int off = 32; off > 0; off >>= 1) {
        s += __shfl_down(s, off);
        c += __shfl_down(c, off);
    }
    const int wv = threadIdx.x >> 6;
    if ((threadIdx.x & 63) == 0) { ss[wv] = s; sc[wv] = c; }
    __syncthreads();
    if (threadIdx.x == 0) {
        float S = ss[0] + ss[1] + ss[2] + ss[3];
        float C = sc[0] + sc[1] + sc[2] + sc[3];
        out_loss[0] = -S / fmaxf(C, 1.0f);
    }
}

extern "C" void kernel_launch(void* const* d_in, const int* in_sizes, int n_in,
                              void* d_out, int out_size, void* d_ws, size_t ws_size,
                              hipStream_t stream)
{
    const float* x   = (const float*)d_in[0];
    const float* y   = (const float*)d_in[1];
    const float* ob  = (const float*)d_in[2];
    const float* cb  = (const float*)d_in[3];
    const float* W1  = (const float*)d_in[4];
    const float* b1  = (const float*)d_in[5];
    const float* W2  = (const float*)d_in[6];
    const float* b2  = (const float*)d_in[7];
    const float* W3  = (const float*)d_in[8];
    const float* b3  = (const float*)d_in[9];
    const int*   neg = (const int*)d_in[10];

    const int B = in_sizes[0] / DIM;        // 131072
    const int nblk = B / RPB;               // 2048

    float*  out_wu = (float*)d_out;
    float2* part   = (float2*)d_ws;         // 16 KiB scratch

    fused_mf2<<<nblk, TPB, 0, stream>>>(x, y, ob, cb, W1, b1, W2, b2, W3, b3,
                                        neg, out_wu, part);
    finalize_k<<<1, TPB, 0, stream>>>(part, nblk, out_wu + (long)B * NA);
}